// Round 10
// baseline (17127.069 us; speedup 1.0000x reference)
//
#include <hip/hip_runtime.h>

#define TSTEPS 8192
#define NDIM   2048
#define NBLK   128
#define NTHR   1024   // 16 waves: 1 row/wave -> W = 32 VGPR/thread, fits the
                      // allocator's ~64-reg budget (rounds 3-9: 2 rows/wave
                      // = 64 VGPR of W always got half-spilled to scratch)
#define RPB    16     // rows per block = NDIM/NBLK
#define NREP   16     // state replicas (round 9: -8%): readers/line 512 -> 32

typedef float    f32x4 __attribute__((ext_vector_type(4)));
typedef unsigned u32x4 __attribute__((ext_vector_type(4)));

// Agent-scope (device-coherent, sc1) ops — coherence point is the shared LLC.
__device__ __forceinline__ unsigned ld_u32_agent(const unsigned* p) {
  return __hip_atomic_load((unsigned*)p, __ATOMIC_RELAXED, __HIP_MEMORY_SCOPE_AGENT);
}
__device__ __forceinline__ void st_u32_agent(unsigned* p, unsigned v) {
  __hip_atomic_store(p, v, __ATOMIC_RELAXED, __HIP_MEMORY_SCOPE_AGENT);
}
// One 16B device-coherent load, completion fused in-asm.
__device__ __forceinline__ u32x4 ld_x4_agent(const u32x4* p) {
  u32x4 r;
  asm volatile("global_load_dwordx4 %0, %1, off sc1\n\ts_waitcnt vmcnt(0)"
               : "=v"(r) : "v"(p) : "memory");
  return r;
}
__device__ __forceinline__ void st_x4_agent(u32x4* p, u32x4 v) {
  asm volatile("global_store_dwordx4 %0, %1, off sc1" :: "v"(p), "v"(v) : "memory");
}
// W preload: value is an ASM OUTPUT (cannot be re-materialized as a reload).
__device__ __forceinline__ f32x4 ld_w_sync(const f32x4* p) {
  f32x4 r;
  asm volatile("global_load_dwordx4 %0, %1, off\n\ts_waitcnt vmcnt(0)"
               : "=v"(r) : "v"(p));
  return r;
}

__global__ void __launch_bounds__(NTHR, 1) esn_persistent(
    const float* __restrict__ u,
    const float* __restrict__ W_in,
    const float* __restrict__ W_res,
    const int* __restrict__ washout_p,
    float* __restrict__ out,
    unsigned* __restrict__ ws)
{
  const int tid  = threadIdx.x;
  const int bid  = blockIdx.x;
  const int wave = tid >> 6;
  const int lane = tid & 63;
  const int row  = bid * RPB + wave;      // this wave owns ONE row
  const int washout = washout_p[0];

  // ws layout (zeroed by hipMemsetAsync each launch):
  //   u32[144]    : abort word (own line)
  //   byte 1024+  : NREP replicas x 2 parities x 2048 u32 packed state
  //                 word[i] = (bf16(x[i]) << 16) | step_tag16   (0 == x0=0 @ t=0)
  unsigned* abortw  = ws + 144;
  unsigned* repbase = ws + 256;       // byte offset 1024

  __shared__ __align__(16) float    x_lds[NDIM];
  __shared__ __align__(16) unsigned xpack_lds[RPB];  // block's 16 packed words (one 64B line)
  __shared__ __align__(16) float    xval_lds[RPB];   // block's 16 f32 values (out row)
  __shared__ int s_abort;
  if (tid == 0) s_abort = 0;

  // ---- W preload: ONE row per wave = 8 asm-defined f32x4 = 32 VGPRs. ----
  const f32x4* Wr = (const f32x4*)(W_res + (size_t)row * NDIM) + lane;
  const f32x4 w0 = ld_w_sync(Wr + 0 * 64), w1 = ld_w_sync(Wr + 1 * 64);
  const f32x4 w2 = ld_w_sync(Wr + 2 * 64), w3 = ld_w_sync(Wr + 3 * 64);
  const f32x4 w4 = ld_w_sync(Wr + 4 * 64), w5 = ld_w_sync(Wr + 5 * 64);
  const f32x4 w6 = ld_w_sync(Wr + 6 * 64), w7 = ld_w_sync(Wr + 7 * 64);
  const float win = W_in[row];

  // This block polls ONLY its private replica (bid & 15): 8 blocks per replica
  // -> 32 readers per 64B line.
  unsigned* myrep0 = repbase + ((unsigned)(bid & (NREP - 1)) * 2) * NDIM;

  for (int t = 0; t < TSTEPS; ++t) {
    // ---- fused poll+stage (threads 0-511; waves 8-15 wait at S_a): ONE
    // dwordx4 per thread from the private replica, retried until all 4
    // embedded tags == t. ----
    if (tid < 512) {
      const u32x4* src = (const u32x4*)(myrep0 + (t & 1) * NDIM) + tid;
      const unsigned want = (unsigned)t;
      u32x4 r;
      bool ok;
      {
        unsigned g = 0;
        do {
          r = ld_x4_agent(src);
          ok = ((((r.x ^ want) | (r.y ^ want)) |
                 ((r.z ^ want) | (r.w ^ want))) & 0xFFFFu) == 0u;
          if (!ok && ((++g & 255u) == 0u)) {
            if (ld_u32_agent(abortw) != 0u) break;
            if (g > (1u << 20)) { st_u32_agent(abortw, 1u); break; }
          }
        } while (!ok);
      }
      if (!ok) s_abort = 1;
      f32x4 xv;   // unpack bf16 (high 16 bits) -> f32: one AND per element
      xv.x = __uint_as_float(r.x & 0xFFFF0000u);
      xv.y = __uint_as_float(r.y & 0xFFFF0000u);
      xv.z = __uint_as_float(r.z & 0xFFFF0000u);
      xv.w = __uint_as_float(r.w & 0xFFFF0000u);
      ((f32x4*)x_lds)[tid] = xv;
    }
    const float ut = u[t];                 // uniform, cached; hides under S_a
    __syncthreads();                       // S_a
    if (s_abort) return;                   // fail loudly instead of hanging

    // ---- 1 dot product per wave: W from resident VGPRs, x from LDS. ----
    float a0 = 0.f, b0 = 0.f;
    const f32x4* x4v = (const f32x4*)x_lds + lane;
#define ESN_DOT(WA, K, A) { const f32x4 xv = x4v[(K) * 64];                   \
      A += WA.x * xv.x; A += WA.y * xv.y; A += WA.z * xv.z; A += WA.w * xv.w; }
    ESN_DOT(w0, 0, a0) ESN_DOT(w1, 1, b0)
    ESN_DOT(w2, 2, a0) ESN_DOT(w3, 3, b0)
    ESN_DOT(w4, 4, a0) ESN_DOT(w5, 5, b0)
    ESN_DOT(w6, 6, a0) ESN_DOT(w7, 7, b0)
#undef ESN_DOT
    float c = a0 + b0;
#pragma unroll
    for (int off = 32; off > 0; off >>= 1) c += __shfl_xor(c, off, 64);

    if (lane == 0) {
      const float pre = win * ut + c;
      const float e2  = __expf(2.0f * pre);            // tanh = 1 - 2/(e^2x + 1)
      const float th  = 1.0f - __fdividef(2.0f, e2 + 1.0f);
      xval_lds[wave] = th;
      const unsigned b  = __float_as_uint(th);
      const unsigned bf = (b + 0x7fffu + ((b >> 16) & 1u)) & 0xFFFF0000u; // RNE bf16
      xpack_lds[wave] = bf | (unsigned)(t + 1);        // tag t+1 < 2^16
    }
    __syncthreads();                       // S_b

    // ---- replicated publish: 64 threads store the block's 64B line into all
    // NREP replicas (one 16B store each, issue-parallel, fire-and-forget) ----
    if (tid < 4 * NREP) {
      const int rep = tid >> 2, seg = tid & 3;
      u32x4* dst = (u32x4*)(repbase + ((unsigned)(rep * 2 + ((t + 1) & 1)) * NDIM))
                   + bid * 4 + seg;
      st_x4_agent(dst, ((const u32x4*)xpack_lds)[seg]);
    } else if (tid >= 64 && tid < 68 && t >= washout) {  // output row (wave 1)
      float4* orow = (float4*)(out + (size_t)(t - washout) * NDIM) + bid * 4 + (tid - 64);
      const f32x4 vv = ((const f32x4*)xval_lds)[tid - 64];
      float4 v; v.x = vv.x; v.y = vv.y; v.z = vv.z; v.w = vv.w;
      *orow = v;
    }
  }
}

extern "C" void kernel_launch(void* const* d_in, const int* in_sizes, int n_in,
                              void* d_out, int out_size, void* d_ws, size_t ws_size,
                              hipStream_t stream) {
  const float* u       = (const float*)d_in[0];
  const float* W_in    = (const float*)d_in[1];
  const float* W_res   = (const float*)d_in[2];
  const int*   washout = (const int*)d_in[3];
  float*       out     = (float*)d_out;

  // Zero abort word + all replica parity buffers (tag 0 == valid x0 = zeros).
  // Captured in the graph, so every replay starts from identical state.
  (void)hipMemsetAsync(d_ws, 0, 1024 + NREP * 2 * NDIM * 4, stream);

  esn_persistent<<<dim3(NBLK), dim3(NTHR), 0, stream>>>(
      u, W_in, W_res, washout, out, (unsigned*)d_ws);
}